// Round 1
// baseline (458.605 us; speedup 1.0000x reference)
//
#include <hip/hip_runtime.h>
#include <math.h>

#define N_NODES 50000
#define N_EDGES 800000
#define BIGV 1000000000.0f

__device__ __forceinline__ float clampinf(float x) { return isinf(x) ? BIGV : x; }

// ---------------------------------------------------------------------------
// K1: z = h @ W + b  (fp32, 50000x128 @ 128x128), fused per-node attention
// scores s = z . w_src, t = z . w_dst.
// Block 256 threads = 16 nodes. tx=col-quad (4 cols), ty=row slot (2 rows).
// ---------------------------------------------------------------------------
__global__ __launch_bounds__(256) void k_gemm(
    const float* __restrict__ h, const float* __restrict__ W,
    const float* __restrict__ bias, const float* __restrict__ attn_w,
    float* __restrict__ z, float* __restrict__ sv, float* __restrict__ tv)
{
    __shared__ float hs[16][128];
    const int tid = threadIdx.x;
    const int tx = tid & 31, ty = tid >> 5;
    const int node0 = blockIdx.x << 4;

    const float4* h4 = (const float4*)(h + (size_t)node0 * 128);
    float4* hs4 = (float4*)&hs[0][0];
    for (int i = tid; i < 512; i += 256) hs4[i] = h4[i];
    __syncthreads();

    const float4 b4 = ((const float4*)bias)[tx];
    float4 a0 = b4, a1 = b4;
    const int r0 = ty, r1 = ty + 8;
    for (int k = 0; k < 128; ++k) {
        float4 w4 = ((const float4*)W)[k * 32 + tx];
        float h0 = hs[r0][k], h1 = hs[r1][k];
        a0.x = fmaf(h0, w4.x, a0.x); a0.y = fmaf(h0, w4.y, a0.y);
        a0.z = fmaf(h0, w4.z, a0.z); a0.w = fmaf(h0, w4.w, a0.w);
        a1.x = fmaf(h1, w4.x, a1.x); a1.y = fmaf(h1, w4.y, a1.y);
        a1.z = fmaf(h1, w4.z, a1.z); a1.w = fmaf(h1, w4.w, a1.w);
    }
    a0.x = clampinf(a0.x); a0.y = clampinf(a0.y);
    a0.z = clampinf(a0.z); a0.w = clampinf(a0.w);
    a1.x = clampinf(a1.x); a1.y = clampinf(a1.y);
    a1.z = clampinf(a1.z); a1.w = clampinf(a1.w);

    ((float4*)z)[(size_t)(node0 + r0) * 32 + tx] = a0;
    ((float4*)z)[(size_t)(node0 + r1) * 32 + tx] = a1;

    // fused per-node scores
    const float4 ws4 = ((const float4*)attn_w)[tx];
    const float4 wd4 = ((const float4*)attn_w)[32 + tx];
    float p0s = a0.x*ws4.x + a0.y*ws4.y + a0.z*ws4.z + a0.w*ws4.w;
    float p0t = a0.x*wd4.x + a0.y*wd4.y + a0.z*wd4.z + a0.w*wd4.w;
    float p1s = a1.x*ws4.x + a1.y*ws4.y + a1.z*ws4.z + a1.w*ws4.w;
    float p1t = a1.x*wd4.x + a1.y*wd4.y + a1.z*wd4.z + a1.w*wd4.w;
    for (int o = 16; o; o >>= 1) {   // xor masks <32 keep the 32-lane halves (ty groups) independent
        p0s += __shfl_xor(p0s, o); p0t += __shfl_xor(p0t, o);
        p1s += __shfl_xor(p1s, o); p1t += __shfl_xor(p1t, o);
    }
    if (tx == 0) {
        sv[node0 + r0] = p0s; tv[node0 + r0] = p0t;
        sv[node0 + r1] = p1s; tv[node0 + r1] = p1t;
    }
}

// ---------------------------------------------------------------------------
// CSR build: histogram -> single-block scan -> scatter
// ---------------------------------------------------------------------------
__global__ void k_hist(const int* __restrict__ dst, int* __restrict__ cursor)
{
    int e = blockIdx.x * 256 + threadIdx.x;
    if (e < N_EDGES) atomicAdd(&cursor[dst[e]], 1);
}

// single block, 1024 threads; reads counts from cursor, writes exclusive
// prefix into colptr AND resets cursor[i] to the same prefix (scatter cursors)
__global__ __launch_bounds__(1024) void k_scan(int* __restrict__ cursor,
                                               int* __restrict__ colptr)
{
    __shared__ int lds[1024];
    const int t = threadIdx.x;
    const int CH = (N_NODES + 1023) / 1024;   // 49
    const int start = t * CH;
    const int end = min(start + CH, N_NODES);
    int local = 0;
    for (int i = start; i < end; ++i) local += cursor[i];
    lds[t] = local;
    __syncthreads();
    for (int off = 1; off < 1024; off <<= 1) {
        int v = (t >= off) ? lds[t - off] : 0;
        __syncthreads();
        if (t >= off) lds[t] += v;
        __syncthreads();
    }
    int run = (t > 0) ? lds[t - 1] : 0;
    for (int i = start; i < end; ++i) {
        int c = cursor[i];
        colptr[i] = run;
        cursor[i] = run;
        run += c;
    }
    if (t == 1023) colptr[N_NODES] = lds[1023];
}

__global__ void k_scatter(const int* __restrict__ src, const int* __restrict__ dst,
                          const float* __restrict__ sigma, int* __restrict__ cursor,
                          int* __restrict__ src_perm, float* __restrict__ sigma_perm)
{
    int e = blockIdx.x * 256 + threadIdx.x;
    if (e < N_EDGES) {
        int d = dst[e];
        int pos = atomicAdd(&cursor[d], 1);
        src_perm[pos] = src[e];
        sigma_perm[pos] = sigma[e];
    }
}

// ---------------------------------------------------------------------------
// K6: per-node softmax + weighted aggregate. One 64-lane wave per node.
// passes: (1) max, (2) denom & sigma-sum, (3) recompute coef + accumulate
// z[src] rows with lanes over the 128 features.
// ---------------------------------------------------------------------------
__global__ __launch_bounds__(256) void k_agg(
    const int* __restrict__ colptr, const int* __restrict__ src_perm,
    const float* __restrict__ sigma_perm, const float* __restrict__ sv,
    const float* __restrict__ tv, const float* __restrict__ attn_b,
    const float* __restrict__ z, float* __restrict__ out)
{
    const int lane = threadIdx.x & 63;
    const int node = blockIdx.x * 4 + (threadIdx.x >> 6);
    if (node >= N_NODES) return;
    const int base = colptr[node];
    const int deg = colptr[node + 1] - base;

    float acc0 = 0.f, acc1 = 0.f;
    if (deg > 0) {
        const float ab = attn_b[0];
        const float tn = tv[node];
        // pass 1: max
        float m = -INFINITY;
        for (int c = 0; c < deg; c += 64) {
            int i = c + lane;
            float e = -INFINITY;
            if (i < deg) {
                float a = sv[src_perm[base + i]] + tn + ab;
                a = clampinf(a);
                e = a > 0.f ? a : 0.01f * a;
            }
            m = fmaxf(m, e);
        }
        for (int o = 32; o; o >>= 1) m = fmaxf(m, __shfl_xor(m, o));
        // pass 2: softmax denom + sigma sum
        float denom = 0.f, bsum = 0.f;
        for (int c = 0; c < deg; c += 64) {
            int i = c + lane;
            if (i < deg) {
                float a = sv[src_perm[base + i]] + tn + ab;
                a = clampinf(a);
                float e = a > 0.f ? a : 0.01f * a;
                denom += __expf(e - m);
                bsum += sigma_perm[base + i];
            }
        }
        for (int o = 32; o; o >>= 1) {
            denom += __shfl_xor(denom, o);
            bsum  += __shfl_xor(bsum, o);
        }
        const float inv_d = 1.0f / denom;
        const float inv_b = 1.0f / (bsum + 1e-6f);
        // pass 3: coefficients + vector accumulate
        for (int c = 0; c < deg; c += 64) {
            int i = c + lane;
            float coef = 0.f;
            int sidx = 0;
            if (i < deg) {
                sidx = src_perm[base + i];
                float a = sv[sidx] + tn + ab;
                a = clampinf(a);
                float e = a > 0.f ? a : 0.01f * a;
                coef = __expf(e - m) * inv_d * (sigma_perm[base + i] * inv_b);
            }
            int cnt = min(64, deg - c);
            for (int j = 0; j < cnt; ++j) {
                float cf = __shfl(coef, j);
                int sj = __shfl(sidx, j);
                const float* zr = z + ((size_t)sj << 7);
                acc0 = fmaf(cf, zr[lane], acc0);
                acc1 = fmaf(cf, zr[lane + 64], acc1);
            }
        }
    }
    out[(size_t)node * 128 + lane]      = clampinf(acc0);
    out[(size_t)node * 128 + 64 + lane] = clampinf(acc1);
}

// ---------------------------------------------------------------------------
// BatchNorm: per-feature sum / sumsq partials + atomics, then fused apply+ELU
// ---------------------------------------------------------------------------
__global__ __launch_bounds__(256) void k_bnstats(const float* __restrict__ hnew,
                                                 float* __restrict__ sums)
{
    const int f = threadIdx.x & 127;
    const int half = threadIdx.x >> 7;   // 0..1
    float s = 0.f, q = 0.f;
    for (int node = blockIdx.x * 2 + half; node < N_NODES; node += gridDim.x * 2) {
        float v = hnew[(size_t)node * 128 + f];
        s += v;
        q += v * v;
    }
    __shared__ float ls[256], lq[256];
    ls[threadIdx.x] = s; lq[threadIdx.x] = q;
    __syncthreads();
    if (half == 0) {
        s += ls[threadIdx.x + 128];
        q += lq[threadIdx.x + 128];
        atomicAdd(&sums[f], s);
        atomicAdd(&sums[128 + f], q);
    }
}

__global__ __launch_bounds__(256) void k_bnapply(float* __restrict__ io,
                                                 const float* __restrict__ sums,
                                                 const float* __restrict__ gamma,
                                                 const float* __restrict__ beta)
{
    const size_t idx = (size_t)blockIdx.x * 256 + threadIdx.x;
    const int f = (int)(idx & 127);
    const float invn = 1.0f / (float)N_NODES;
    float mu = sums[f] * invn;
    float var = fmaxf(sums[128 + f] * invn - mu * mu, 0.f);
    float rs = rsqrtf(var + 1e-5f);
    float x = io[idx];
    float y = (x - mu) * rs * gamma[f] + beta[f];
    io[idx] = y > 0.f ? y : expm1f(y);
}

// ---------------------------------------------------------------------------
extern "C" void kernel_launch(void* const* d_in, const int* in_sizes, int n_in,
                              void* d_out, int out_size, void* d_ws, size_t ws_size,
                              hipStream_t stream)
{
    const float* h      = (const float*)d_in[0];
    const int*   src    = (const int*)  d_in[1];
    const int*   dst    = (const int*)  d_in[2];
    const float* sigma  = (const float*)d_in[3];
    const float* fc_w   = (const float*)d_in[4];
    const float* fc_b   = (const float*)d_in[5];
    const float* attn_w = (const float*)d_in[6];
    const float* attn_b = (const float*)d_in[7];
    const float* gamma  = (const float*)d_in[8];
    const float* beta   = (const float*)d_in[9];
    float* out = (float*)d_out;

    // workspace layout (~33 MB)
    float* z          = (float*)d_ws;                       // 50000*128
    float* sv         = z + (size_t)N_NODES * 128;          // 50000
    float* tv         = sv + N_NODES;                       // 50000
    float* bns        = tv + N_NODES;                       // 256
    int*   colptr     = (int*)(bns + 256);                  // 50001 (pad 50004)
    int*   cursor     = colptr + 50004;                     // 50000
    int*   src_perm   = cursor + N_NODES;                   // 800000
    float* sigma_perm = (float*)(src_perm + N_EDGES);       // 800000

    hipMemsetAsync(cursor, 0, N_NODES * sizeof(int), stream);
    hipMemsetAsync(bns, 0, 256 * sizeof(float), stream);

    k_gemm   <<<N_NODES / 16, 256, 0, stream>>>(h, fc_w, fc_b, attn_w, z, sv, tv);
    k_hist   <<<N_EDGES / 256, 256, 0, stream>>>(dst, cursor);
    k_scan   <<<1, 1024, 0, stream>>>(cursor, colptr);
    k_scatter<<<N_EDGES / 256, 256, 0, stream>>>(src, dst, sigma, cursor,
                                                 src_perm, sigma_perm);
    k_agg    <<<N_NODES / 4, 256, 0, stream>>>(colptr, src_perm, sigma_perm,
                                               sv, tv, attn_b, z, out);
    k_bnstats<<<256, 256, 0, stream>>>(out, bns);
    k_bnapply<<<(N_NODES * 128) / 256, 256, 0, stream>>>(out, bns, gamma, beta);
}

// Round 2
// 349.399 us; speedup vs baseline: 1.3126x; 1.3126x over previous
//
#include <hip/hip_runtime.h>
#include <math.h>

#define N_NODES 50000
#define N_EDGES 800000
#define BIGV 1000000000.0f
#define NBLK_SCAN 196   // ceil(50000/256)

__device__ __forceinline__ float clampinf(float x) { return isinf(x) ? BIGV : x; }

// ---------------------------------------------------------------------------
// K1: z = h @ W + b  (fp32, 50000x128 @ 128x128), fused per-node attention
// scores s = z . w_src, t = z . w_dst.
// Block 256 threads = 16 nodes. tx=col-quad (4 cols), ty=row slot (2 rows).
// ---------------------------------------------------------------------------
__global__ __launch_bounds__(256) void k_gemm(
    const float* __restrict__ h, const float* __restrict__ W,
    const float* __restrict__ bias, const float* __restrict__ attn_w,
    float* __restrict__ z, float* __restrict__ sv, float* __restrict__ tv)
{
    __shared__ float hs[16][128];
    const int tid = threadIdx.x;
    const int tx = tid & 31, ty = tid >> 5;
    const int node0 = blockIdx.x << 4;

    const float4* h4 = (const float4*)(h + (size_t)node0 * 128);
    float4* hs4 = (float4*)&hs[0][0];
    for (int i = tid; i < 512; i += 256) hs4[i] = h4[i];
    __syncthreads();

    const float4 b4 = ((const float4*)bias)[tx];
    float4 a0 = b4, a1 = b4;
    const int r0 = ty, r1 = ty + 8;
    for (int k = 0; k < 128; ++k) {
        float4 w4 = ((const float4*)W)[k * 32 + tx];
        float h0 = hs[r0][k], h1 = hs[r1][k];
        a0.x = fmaf(h0, w4.x, a0.x); a0.y = fmaf(h0, w4.y, a0.y);
        a0.z = fmaf(h0, w4.z, a0.z); a0.w = fmaf(h0, w4.w, a0.w);
        a1.x = fmaf(h1, w4.x, a1.x); a1.y = fmaf(h1, w4.y, a1.y);
        a1.z = fmaf(h1, w4.z, a1.z); a1.w = fmaf(h1, w4.w, a1.w);
    }
    a0.x = clampinf(a0.x); a0.y = clampinf(a0.y);
    a0.z = clampinf(a0.z); a0.w = clampinf(a0.w);
    a1.x = clampinf(a1.x); a1.y = clampinf(a1.y);
    a1.z = clampinf(a1.z); a1.w = clampinf(a1.w);

    ((float4*)z)[(size_t)(node0 + r0) * 32 + tx] = a0;
    ((float4*)z)[(size_t)(node0 + r1) * 32 + tx] = a1;

    // fused per-node scores
    const float4 ws4 = ((const float4*)attn_w)[tx];
    const float4 wd4 = ((const float4*)attn_w)[32 + tx];
    float p0s = a0.x*ws4.x + a0.y*ws4.y + a0.z*ws4.z + a0.w*ws4.w;
    float p0t = a0.x*wd4.x + a0.y*wd4.y + a0.z*wd4.z + a0.w*wd4.w;
    float p1s = a1.x*ws4.x + a1.y*ws4.y + a1.z*ws4.z + a1.w*ws4.w;
    float p1t = a1.x*wd4.x + a1.y*wd4.y + a1.z*wd4.z + a1.w*wd4.w;
    for (int o = 16; o; o >>= 1) {   // xor masks <32 keep the 32-lane halves independent
        p0s += __shfl_xor(p0s, o); p0t += __shfl_xor(p0t, o);
        p1s += __shfl_xor(p1s, o); p1t += __shfl_xor(p1t, o);
    }
    if (tx == 0) {
        sv[node0 + r0] = p0s; tv[node0 + r0] = p0t;
        sv[node0 + r1] = p1s; tv[node0 + r1] = p1t;
    }
}

// ---------------------------------------------------------------------------
// CSR build: histogram -> hierarchical scan -> scatter (+ fused edge scores)
// ---------------------------------------------------------------------------
__global__ void k_hist(const int* __restrict__ dst, int* __restrict__ cursor)
{
    int e = blockIdx.x * 256 + threadIdx.x;
    if (e < N_EDGES) atomicAdd(&cursor[dst[e]], 1);
}

// phase 1: per-block sums of cursor
__global__ __launch_bounds__(256) void k_scan_bsum(const int* __restrict__ cursor,
                                                   int* __restrict__ bsum)
{
    __shared__ int s[256];
    const int t = threadIdx.x;
    const int idx = blockIdx.x * 256 + t;
    int v = (idx < N_NODES) ? cursor[idx] : 0;
    s[t] = v;
    __syncthreads();
    for (int off = 128; off; off >>= 1) {
        if (t < off) s[t] += s[t + off];
        __syncthreads();
    }
    if (t == 0) bsum[blockIdx.x] = s[0];
}

// phase 2: single block scans the 196 block sums -> exclusive offsets
__global__ __launch_bounds__(256) void k_scan_root(const int* __restrict__ bsum,
                                                   int* __restrict__ broot,
                                                   int* __restrict__ colptr)
{
    __shared__ int s[256];
    const int t = threadIdx.x;
    int v = (t < NBLK_SCAN) ? bsum[t] : 0;
    s[t] = v;
    __syncthreads();
    for (int off = 1; off < 256; off <<= 1) {
        int u = (t >= off) ? s[t - off] : 0;
        __syncthreads();
        s[t] += u;
        __syncthreads();
    }
    if (t < NBLK_SCAN) broot[t] = s[t] - v;      // exclusive
    if (t == 255) colptr[N_NODES] = s[255];      // total = N_EDGES
}

// phase 3: block-local exclusive scan + root offset -> colptr & cursor
__global__ __launch_bounds__(256) void k_scan_final(const int* __restrict__ cursor_in,
                                                    const int* __restrict__ broot,
                                                    int* __restrict__ colptr,
                                                    int* __restrict__ cursor_out)
{
    __shared__ int s[256];
    const int t = threadIdx.x;
    const int idx = blockIdx.x * 256 + t;
    int v = (idx < N_NODES) ? cursor_in[idx] : 0;
    s[t] = v;
    __syncthreads();
    for (int off = 1; off < 256; off <<= 1) {
        int u = (t >= off) ? s[t - off] : 0;
        __syncthreads();
        s[t] += u;
        __syncthreads();
    }
    if (idx < N_NODES) {
        int pos = broot[blockIdx.x] + s[t] - v;  // exclusive prefix
        colptr[idx] = pos;
        cursor_out[idx] = pos;
    }
}

// scatter edges into CSR order; fuse the edge score computation so k_agg
// only ever reads coalesced arrays.
__global__ void k_scatter(const int* __restrict__ src, const int* __restrict__ dst,
                          const float* __restrict__ sigma,
                          const float* __restrict__ sv, const float* __restrict__ tv,
                          const float* __restrict__ attn_b,
                          int* __restrict__ cursor,
                          int* __restrict__ src_perm, float* __restrict__ sigma_perm,
                          float* __restrict__ e_perm)
{
    int e = blockIdx.x * 256 + threadIdx.x;
    if (e < N_EDGES) {
        int s = src[e];
        int d = dst[e];
        float a = sv[s] + tv[d] + attn_b[0];
        a = clampinf(a);
        float ev = a > 0.f ? a : 0.01f * a;      // leaky relu
        int pos = atomicAdd(&cursor[d], 1);
        src_perm[pos] = s;
        sigma_perm[pos] = sigma[e];
        e_perm[pos] = ev;
    }
}

// ---------------------------------------------------------------------------
// K6: per-node softmax + weighted aggregate. One 64-lane wave per node.
// All edge-order reads are coalesced (e_perm/sigma_perm/src_perm).
// ---------------------------------------------------------------------------
__global__ __launch_bounds__(256) void k_agg(
    const int* __restrict__ colptr, const int* __restrict__ src_perm,
    const float* __restrict__ sigma_perm, const float* __restrict__ e_perm,
    const float* __restrict__ z, float* __restrict__ out)
{
    const int lane = threadIdx.x & 63;
    const int node = blockIdx.x * 4 + (threadIdx.x >> 6);
    if (node >= N_NODES) return;
    const int base = colptr[node];
    const int deg = colptr[node + 1] - base;

    float2 acc = {0.f, 0.f};
    if (deg > 0) {
        // pass 1: max
        float m = -INFINITY;
        for (int i = lane; i < deg; i += 64) m = fmaxf(m, e_perm[base + i]);
        for (int o = 32; o; o >>= 1) m = fmaxf(m, __shfl_xor(m, o));
        // pass 2: softmax denom + sigma sum
        float denom = 0.f, bsumv = 0.f;
        for (int i = lane; i < deg; i += 64) {
            denom += __expf(e_perm[base + i] - m);
            bsumv += sigma_perm[base + i];
        }
        for (int o = 32; o; o >>= 1) {
            denom += __shfl_xor(denom, o);
            bsumv += __shfl_xor(bsumv, o);
        }
        const float scale = (1.0f / denom) / (bsumv + 1e-6f);
        // pass 3: coefficients + vector accumulate
        for (int c = 0; c < deg; c += 64) {
            int i = c + lane;
            float coef = 0.f;
            int sidx = 0;
            if (i < deg) {
                sidx = src_perm[base + i];
                coef = __expf(e_perm[base + i] - m) * sigma_perm[base + i] * scale;
            }
            int cnt = min(64, deg - c);
            for (int j = 0; j < cnt; ++j) {
                float cf = __shfl(coef, j);
                int sj = __shfl(sidx, j);
                const float2 zr = ((const float2*)(z + ((size_t)sj << 7)))[lane];
                acc.x = fmaf(cf, zr.x, acc.x);
                acc.y = fmaf(cf, zr.y, acc.y);
            }
        }
    }
    float2 o2;
    o2.x = clampinf(acc.x);
    o2.y = clampinf(acc.y);
    ((float2*)(out + (size_t)node * 128))[lane] = o2;
}

// ---------------------------------------------------------------------------
// BatchNorm: per-feature sum / sumsq partials + atomics, then fused apply+ELU
// ---------------------------------------------------------------------------
__global__ __launch_bounds__(256) void k_bnstats(const float* __restrict__ hnew,
                                                 float* __restrict__ sums)
{
    const int f = threadIdx.x & 127;
    const int half = threadIdx.x >> 7;
    float s = 0.f, q = 0.f;
    for (int node = blockIdx.x * 2 + half; node < N_NODES; node += gridDim.x * 2) {
        float v = hnew[(size_t)node * 128 + f];
        s += v;
        q += v * v;
    }
    __shared__ float ls[256], lq[256];
    ls[threadIdx.x] = s; lq[threadIdx.x] = q;
    __syncthreads();
    if (half == 0) {
        s += ls[threadIdx.x + 128];
        q += lq[threadIdx.x + 128];
        atomicAdd(&sums[f], s);
        atomicAdd(&sums[128 + f], q);
    }
}

__global__ __launch_bounds__(256) void k_bnapply(float* __restrict__ io,
                                                 const float* __restrict__ sums,
                                                 const float* __restrict__ gamma,
                                                 const float* __restrict__ beta)
{
    const size_t idx = (size_t)blockIdx.x * 256 + threadIdx.x;
    const int f = (int)(idx & 127);
    const float invn = 1.0f / (float)N_NODES;
    float mu = sums[f] * invn;
    float var = fmaxf(sums[128 + f] * invn - mu * mu, 0.f);
    float rs = rsqrtf(var + 1e-5f);
    float x = io[idx];
    float y = (x - mu) * rs * gamma[f] + beta[f];
    io[idx] = y > 0.f ? y : expm1f(y);
}

// ---------------------------------------------------------------------------
extern "C" void kernel_launch(void* const* d_in, const int* in_sizes, int n_in,
                              void* d_out, int out_size, void* d_ws, size_t ws_size,
                              hipStream_t stream)
{
    const float* h      = (const float*)d_in[0];
    const int*   src    = (const int*)  d_in[1];
    const int*   dst    = (const int*)  d_in[2];
    const float* sigma  = (const float*)d_in[3];
    const float* fc_w   = (const float*)d_in[4];
    const float* fc_b   = (const float*)d_in[5];
    const float* attn_w = (const float*)d_in[6];
    const float* attn_b = (const float*)d_in[7];
    const float* gamma  = (const float*)d_in[8];
    const float* beta   = (const float*)d_in[9];
    float* out = (float*)d_out;

    // workspace layout (~37 MB)
    float* z          = (float*)d_ws;                       // 50000*128
    float* sv         = z + (size_t)N_NODES * 128;          // 50000
    float* tv         = sv + N_NODES;                       // 50000
    float* bns        = tv + N_NODES;                       // 256
    int*   colptr     = (int*)(bns + 256);                  // 50001 (pad 50004)
    int*   cursor     = colptr + 50004;                     // 50000
    int*   src_perm   = cursor + N_NODES;                   // 800000
    float* sigma_perm = (float*)(src_perm + N_EDGES);       // 800000
    float* e_perm     = sigma_perm + N_EDGES;               // 800000
    int*   bsum       = (int*)(e_perm + N_EDGES);           // 196 (pad 256)
    int*   broot      = bsum + 256;                         // 196

    hipMemsetAsync(cursor, 0, N_NODES * sizeof(int), stream);
    hipMemsetAsync(bns, 0, 256 * sizeof(float), stream);

    k_gemm      <<<N_NODES / 16, 256, 0, stream>>>(h, fc_w, fc_b, attn_w, z, sv, tv);
    k_hist      <<<N_EDGES / 256, 256, 0, stream>>>(dst, cursor);
    k_scan_bsum <<<NBLK_SCAN, 256, 0, stream>>>(cursor, bsum);
    k_scan_root <<<1, 256, 0, stream>>>(bsum, broot, colptr);
    k_scan_final<<<NBLK_SCAN, 256, 0, stream>>>(cursor, broot, colptr, cursor);
    k_scatter   <<<N_EDGES / 256, 256, 0, stream>>>(src, dst, sigma, sv, tv, attn_b,
                                                    cursor, src_perm, sigma_perm, e_perm);
    k_agg       <<<N_NODES / 4, 256, 0, stream>>>(colptr, src_perm, sigma_perm,
                                                  e_perm, z, out);
    k_bnstats   <<<256, 256, 0, stream>>>(out, bns);
    k_bnapply   <<<(N_NODES * 128) / 256, 256, 0, stream>>>(out, bns, gamma, beta);
}

// Round 4
// 291.302 us; speedup vs baseline: 1.5743x; 1.1994x over previous
//
#include <hip/hip_runtime.h>
#include <hip/hip_fp16.h>
#include <math.h>

#define N_NODES 50000
#define N_EDGES 800000
#define BIGV 1000000000.0f
#define NBLK_SCAN 196   // ceil(50000/256)

__device__ __forceinline__ float clampinf(float x) { return isinf(x) ? BIGV : x; }

// ---------------------------------------------------------------------------
// K1: z = h @ W + b (fp32 accum, fp16 z out), fused per-node attention scores
// s = z.w_src, t = z.w_dst, and fused dst-histogram (grid*block == N_EDGES).
// Block 256 threads = 16 nodes. tx=col-quad (4 cols), ty=row slot (2 rows).
// ---------------------------------------------------------------------------
__global__ __launch_bounds__(256) void k_gemm(
    const float* __restrict__ h, const float* __restrict__ W,
    const float* __restrict__ bias, const float* __restrict__ attn_w,
    const int* __restrict__ dst, __half* __restrict__ zh,
    float* __restrict__ sv, float* __restrict__ tv, int* __restrict__ cursor)
{
    __shared__ float hs[16][128];
    const int tid = threadIdx.x;
    const int tx = tid & 31, ty = tid >> 5;
    const int node0 = blockIdx.x << 4;

    const float4* h4 = (const float4*)(h + (size_t)node0 * 128);
    float4* hs4 = (float4*)&hs[0][0];
    for (int i = tid; i < 512; i += 256) hs4[i] = h4[i];
    __syncthreads();

    const float4 b4 = ((const float4*)bias)[tx];
    float4 a0 = b4, a1 = b4;
    const int r0 = ty, r1 = ty + 8;
    for (int k = 0; k < 128; ++k) {
        float4 w4 = ((const float4*)W)[k * 32 + tx];
        float h0 = hs[r0][k], h1 = hs[r1][k];
        a0.x = fmaf(h0, w4.x, a0.x); a0.y = fmaf(h0, w4.y, a0.y);
        a0.z = fmaf(h0, w4.z, a0.z); a0.w = fmaf(h0, w4.w, a0.w);
        a1.x = fmaf(h1, w4.x, a1.x); a1.y = fmaf(h1, w4.y, a1.y);
        a1.z = fmaf(h1, w4.z, a1.z); a1.w = fmaf(h1, w4.w, a1.w);
    }
    a0.x = clampinf(a0.x); a0.y = clampinf(a0.y);
    a0.z = clampinf(a0.z); a0.w = clampinf(a0.w);
    a1.x = clampinf(a1.x); a1.y = clampinf(a1.y);
    a1.z = clampinf(a1.z); a1.w = clampinf(a1.w);

    // fp16 z rows (aggregation payload)
    union { __half2 h2[2]; uint2 u; } pk0, pk1;
    pk0.h2[0] = __floats2half2_rn(a0.x, a0.y);
    pk0.h2[1] = __floats2half2_rn(a0.z, a0.w);
    pk1.h2[0] = __floats2half2_rn(a1.x, a1.y);
    pk1.h2[1] = __floats2half2_rn(a1.z, a1.w);
    *(uint2*)(zh + (size_t)(node0 + r0) * 128 + 4 * tx) = pk0.u;
    *(uint2*)(zh + (size_t)(node0 + r1) * 128 + 4 * tx) = pk1.u;

    // fused per-node scores (fp32)
    const float4 ws4 = ((const float4*)attn_w)[tx];
    const float4 wd4 = ((const float4*)attn_w)[32 + tx];
    float p0s = a0.x*ws4.x + a0.y*ws4.y + a0.z*ws4.z + a0.w*ws4.w;
    float p0t = a0.x*wd4.x + a0.y*wd4.y + a0.z*wd4.z + a0.w*wd4.w;
    float p1s = a1.x*ws4.x + a1.y*ws4.y + a1.z*ws4.z + a1.w*ws4.w;
    float p1t = a1.x*wd4.x + a1.y*wd4.y + a1.z*wd4.z + a1.w*wd4.w;
    for (int o = 16; o; o >>= 1) {
        p0s += __shfl_xor(p0s, o); p0t += __shfl_xor(p0t, o);
        p1s += __shfl_xor(p1s, o); p1t += __shfl_xor(p1t, o);
    }
    if (tx == 0) {
        sv[node0 + r0] = p0s; tv[node0 + r0] = p0t;
        sv[node0 + r1] = p1s; tv[node0 + r1] = p1t;
    }

    // fused histogram: exactly one edge per thread (3125*256 == 800000)
    const int e = blockIdx.x * 256 + tid;
    atomicAdd(&cursor[dst[e]], 1);
}

// ---------------------------------------------------------------------------
// hierarchical scan: per-block sums -> root scan -> block-local scan
// ---------------------------------------------------------------------------
__global__ __launch_bounds__(256) void k_scan_bsum(const int* __restrict__ cursor,
                                                   int* __restrict__ bsum)
{
    __shared__ int s[256];
    const int t = threadIdx.x;
    const int idx = blockIdx.x * 256 + t;
    s[t] = (idx < N_NODES) ? cursor[idx] : 0;
    __syncthreads();
    for (int off = 128; off; off >>= 1) {
        if (t < off) s[t] += s[t + off];
        __syncthreads();
    }
    if (t == 0) bsum[blockIdx.x] = s[0];
}

__global__ __launch_bounds__(256) void k_scan_root(const int* __restrict__ bsum,
                                                   int* __restrict__ broot,
                                                   int* __restrict__ colptr)
{
    __shared__ int s[256];
    const int t = threadIdx.x;
    int v = (t < NBLK_SCAN) ? bsum[t] : 0;
    s[t] = v;
    __syncthreads();
    for (int off = 1; off < 256; off <<= 1) {
        int u = (t >= off) ? s[t - off] : 0;
        __syncthreads();
        s[t] += u;
        __syncthreads();
    }
    if (t < NBLK_SCAN) broot[t] = s[t] - v;      // exclusive
    if (t == 255) colptr[N_NODES] = s[255];
}

__global__ __launch_bounds__(256) void k_scan_final(const int* __restrict__ cursor_in,
                                                    const int* __restrict__ broot,
                                                    int* __restrict__ colptr,
                                                    int* __restrict__ cursor_out)
{
    __shared__ int s[256];
    const int t = threadIdx.x;
    const int idx = blockIdx.x * 256 + t;
    int v = (idx < N_NODES) ? cursor_in[idx] : 0;
    s[t] = v;
    __syncthreads();
    for (int off = 1; off < 256; off <<= 1) {
        int u = (t >= off) ? s[t - off] : 0;
        __syncthreads();
        s[t] += u;
        __syncthreads();
    }
    if (idx < N_NODES) {
        int pos = broot[blockIdx.x] + s[t] - v;
        colptr[idx] = pos;
        cursor_out[idx] = pos;
    }
}

// ---------------------------------------------------------------------------
// scatter edges into CSR order as ONE 16B record {src, sigma, e, pad}
// ---------------------------------------------------------------------------
__global__ void k_scatter(const int* __restrict__ src, const int* __restrict__ dst,
                          const float* __restrict__ sigma,
                          const float* __restrict__ sv, const float* __restrict__ tv,
                          const float* __restrict__ attn_b,
                          int* __restrict__ cursor, float4* __restrict__ recs)
{
    int e = blockIdx.x * 256 + threadIdx.x;
    if (e < N_EDGES) {
        int s = src[e];
        int d = dst[e];
        float a = sv[s] + tv[d] + attn_b[0];
        a = clampinf(a);
        float ev = a > 0.f ? a : 0.01f * a;      // leaky relu
        int pos = atomicAdd(&cursor[d], 1);
        float4 rec;
        rec.x = __int_as_float(s);
        rec.y = sigma[e];
        rec.z = ev;
        rec.w = 0.f;
        recs[pos] = rec;
    }
}

// ---------------------------------------------------------------------------
// K6: per-node softmax + weighted aggregate. One 64-lane wave per node.
// Fast path deg<=64: one record read, all reductions in-register.
// Gather: 4 groups of 16 lanes -> 4 edges in flight, 16B loads of fp16 rows.
// NOTE: all __shfl executed wave-uniformly (outside divergent guards) —
// ds_bpermute from an inactive source lane is undefined on CDNA.
// ---------------------------------------------------------------------------
__global__ __launch_bounds__(256) void k_agg(
    const int* __restrict__ colptr, const float4* __restrict__ recs,
    const __half* __restrict__ zh, float* __restrict__ out)
{
    const int lane = threadIdx.x & 63;
    const int node = blockIdx.x * 4 + (threadIdx.x >> 6);
    if (node >= N_NODES) return;
    const int base = colptr[node];
    const int deg = colptr[node + 1] - base;

    const int grp = lane >> 4;   // 0..3: which edge of the 4 in flight
    const int l16 = lane & 15;   // feature octet within the row
    float acc[8] = {0.f, 0.f, 0.f, 0.f, 0.f, 0.f, 0.f, 0.f};

    if (deg > 0) {
        if (deg <= 64) {
            // ---- fast path: everything in registers ----
            int sidx = 0; float sig = 0.f, e = -INFINITY;
            if (lane < deg) {
                float4 r = recs[base + lane];
                sidx = __float_as_int(r.x); sig = r.y; e = r.z;
            }
            float m = e;
            for (int o = 32; o; o >>= 1) m = fmaxf(m, __shfl_xor(m, o));
            float p = (lane < deg) ? __expf(e - m) : 0.f;
            float dn = p, bs = sig;
            for (int o = 32; o; o >>= 1) {
                dn += __shfl_xor(dn, o);
                bs += __shfl_xor(bs, o);
            }
            const float coef = p * sig * (1.0f / dn) / (bs + 1e-6f);
            for (int c = 0; c < deg; c += 4) {
                const int j = c + grp;                 // j <= 63 always
                const int js = (j < deg) ? j : 0;      // clamp source index
                float cf = __shfl(coef, js);           // uniform: all lanes
                int sj = __shfl(sidx, js);
                if (j < deg) {
                    uint4 raw = *(const uint4*)(zh + ((size_t)sj << 7) + (l16 << 3));
                    const __half2* hp = (const __half2*)&raw;
                    #pragma unroll
                    for (int k = 0; k < 4; ++k) {
                        float2 f = __half22float2(hp[k]);
                        acc[2*k]   = fmaf(cf, f.x, acc[2*k]);
                        acc[2*k+1] = fmaf(cf, f.y, acc[2*k+1]);
                    }
                }
            }
        } else {
            // ---- generic path (deg > 64, rare) ----
            float m = -INFINITY;
            for (int i = lane; i < deg; i += 64) m = fmaxf(m, recs[base + i].z);
            for (int o = 32; o; o >>= 1) m = fmaxf(m, __shfl_xor(m, o));
            float dn = 0.f, bs = 0.f;
            for (int i = lane; i < deg; i += 64) {
                float4 r = recs[base + i];
                dn += __expf(r.z - m); bs += r.y;
            }
            for (int o = 32; o; o >>= 1) {
                dn += __shfl_xor(dn, o);
                bs += __shfl_xor(bs, o);
            }
            const float scale = (1.0f / dn) / (bs + 1e-6f);
            for (int c = 0; c < deg; c += 64) {
                int i = c + lane;
                int sidx = 0; float coef = 0.f;
                if (i < deg) {
                    float4 r = recs[base + i];
                    sidx = __float_as_int(r.x);
                    coef = __expf(r.z - m) * r.y * scale;
                }
                const int cnt = min(64, deg - c);
                for (int j = 0; j < cnt; j += 4) {
                    const int jj = j + grp;            // jj <= 63 always
                    const int js = (jj < cnt) ? jj : 0;
                    float cf = __shfl(coef, js);       // uniform: all lanes
                    int sj = __shfl(sidx, js);
                    if (jj < cnt) {
                        uint4 raw = *(const uint4*)(zh + ((size_t)sj << 7) + (l16 << 3));
                        const __half2* hp = (const __half2*)&raw;
                        #pragma unroll
                        for (int k = 0; k < 4; ++k) {
                            float2 f = __half22float2(hp[k]);
                            acc[2*k]   = fmaf(cf, f.x, acc[2*k]);
                            acc[2*k+1] = fmaf(cf, f.y, acc[2*k+1]);
                        }
                    }
                }
            }
        }
    }
    // combine the 4 groups: feature 8*l16+k lives in lanes {l16, l16+16, l16+32, l16+48}
    #pragma unroll
    for (int k = 0; k < 8; ++k) {
        acc[k] += __shfl_xor(acc[k], 16);
        acc[k] += __shfl_xor(acc[k], 32);
    }
    if (grp == 0) {
        float4 o0, o1;
        o0.x = clampinf(acc[0]); o0.y = clampinf(acc[1]);
        o0.z = clampinf(acc[2]); o0.w = clampinf(acc[3]);
        o1.x = clampinf(acc[4]); o1.y = clampinf(acc[5]);
        o1.z = clampinf(acc[6]); o1.w = clampinf(acc[7]);
        float4* op = (float4*)(out + (size_t)node * 128 + (l16 << 3));
        op[0] = o0; op[1] = o1;
    }
}

// ---------------------------------------------------------------------------
// BatchNorm: per-feature sum / sumsq partials + atomics, then fused apply+ELU
// ---------------------------------------------------------------------------
__global__ __launch_bounds__(256) void k_bnstats(const float* __restrict__ hnew,
                                                 float* __restrict__ sums)
{
    const int f = threadIdx.x & 127;
    const int half_ = threadIdx.x >> 7;
    float s = 0.f, q = 0.f;
    for (int node = blockIdx.x * 2 + half_; node < N_NODES; node += gridDim.x * 2) {
        float v = hnew[(size_t)node * 128 + f];
        s += v;
        q += v * v;
    }
    __shared__ float ls[256], lq[256];
    ls[threadIdx.x] = s; lq[threadIdx.x] = q;
    __syncthreads();
    if (half_ == 0) {
        s += ls[threadIdx.x + 128];
        q += lq[threadIdx.x + 128];
        atomicAdd(&sums[f], s);
        atomicAdd(&sums[128 + f], q);
    }
}

__global__ __launch_bounds__(256) void k_bnapply(float* __restrict__ io,
                                                 const float* __restrict__ sums,
                                                 const float* __restrict__ gamma,
                                                 const float* __restrict__ beta)
{
    const size_t idx = (size_t)blockIdx.x * 256 + threadIdx.x;
    const int f = (int)(idx & 127);
    const float invn = 1.0f / (float)N_NODES;
    float mu = sums[f] * invn;
    float var = fmaxf(sums[128 + f] * invn - mu * mu, 0.f);
    float rs = rsqrtf(var + 1e-5f);
    float x = io[idx];
    float y = (x - mu) * rs * gamma[f] + beta[f];
    io[idx] = y > 0.f ? y : expm1f(y);
}

// ---------------------------------------------------------------------------
extern "C" void kernel_launch(void* const* d_in, const int* in_sizes, int n_in,
                              void* d_out, int out_size, void* d_ws, size_t ws_size,
                              hipStream_t stream)
{
    const float* h      = (const float*)d_in[0];
    const int*   src    = (const int*)  d_in[1];
    const int*   dst    = (const int*)  d_in[2];
    const float* sigma  = (const float*)d_in[3];
    const float* fc_w   = (const float*)d_in[4];
    const float* fc_b   = (const float*)d_in[5];
    const float* attn_w = (const float*)d_in[6];
    const float* attn_b = (const float*)d_in[7];
    const float* gamma  = (const float*)d_in[8];
    const float* beta   = (const float*)d_in[9];
    float* out = (float*)d_out;

    // workspace layout (~27 MB)
    float4* recs   = (float4*)d_ws;                         // 800000 x 16B
    __half* zh     = (__half*)(recs + N_EDGES);             // 50000*128 fp16
    float*  sv     = (float*)(zh + (size_t)N_NODES * 128);  // 50000
    float*  tv     = sv + N_NODES;                          // 50000
    float*  bns    = tv + N_NODES;                          // 256
    int*    colptr = (int*)(bns + 256);                     // 50001 (pad 50004)
    int*    cursor = colptr + 50004;                        // 50000
    int*    bsum   = cursor + N_NODES;                      // 196 (pad 256)
    int*    broot  = bsum + 256;                            // 196

    hipMemsetAsync(cursor, 0, N_NODES * sizeof(int), stream);
    hipMemsetAsync(bns, 0, 256 * sizeof(float), stream);

    k_gemm      <<<N_NODES / 16, 256, 0, stream>>>(h, fc_w, fc_b, attn_w, dst,
                                                   zh, sv, tv, cursor);
    k_scan_bsum <<<NBLK_SCAN, 256, 0, stream>>>(cursor, bsum);
    k_scan_root <<<1, 256, 0, stream>>>(bsum, broot, colptr);
    k_scan_final<<<NBLK_SCAN, 256, 0, stream>>>(cursor, broot, colptr, cursor);
    k_scatter   <<<N_EDGES / 256, 256, 0, stream>>>(src, dst, sigma, sv, tv, attn_b,
                                                    cursor, recs);
    k_agg       <<<N_NODES / 4, 256, 0, stream>>>(colptr, recs, zh, out);
    k_bnstats   <<<256, 256, 0, stream>>>(out, bns);
    k_bnapply   <<<(N_NODES * 128) / 256, 256, 0, stream>>>(out, bns, gamma, beta);
}

// Round 6
// 264.032 us; speedup vs baseline: 1.7369x; 1.1033x over previous
//
#include <hip/hip_runtime.h>
#include <hip/hip_fp16.h>
#include <math.h>

#define N_NODES 50000
#define N_EDGES 800000
#define BIGV 1000000000.0f
#define NBLK_SCAN 196   // ceil(50000/256)

typedef _Float16 half8 __attribute__((ext_vector_type(8)));
typedef float floatx4 __attribute__((ext_vector_type(4)));

__device__ __forceinline__ float clampinf(float x) { return isinf(x) ? BIGV : x; }

// ---------------------------------------------------------------------------
// W pre-cast: wt[n][k] = (fp16) W[k][n]  (128x128, 32 KB) — run once, tiny.
// ---------------------------------------------------------------------------
__global__ __launch_bounds__(256) void k_wcast(const float* __restrict__ W,
                                               __half* __restrict__ wt)
{
    int idx = blockIdx.x * 256 + threadIdx.x;   // 0..16383
    int n = idx >> 7, k = idx & 127;
    wt[idx] = __float2half(W[k * 128 + n]);
}

// ---------------------------------------------------------------------------
// K1: z = h @ W + b via MFMA f16 (fp32 accum), fp16 z out, fused per-node
// attention scores s = z.w_src, t = z.w_dst, fused dst-histogram.
// Block 256 = 4 waves; block does 16 nodes x 128 cols; wave w: cols [32w,32w+32).
// Fragment layouts (m89-verified):
//   A[m=lane&15][k=oct*8+j], B[k=oct*8+j][n=lane&15], C/D col=lane&15,
//   row=oct*4+reg  (oct = lane>>4).
// LDS rows padded +8 halves -> 2-way bank aliasing only (free).
// ---------------------------------------------------------------------------
__global__ __launch_bounds__(256) void k_gemm(
    const float* __restrict__ h, const __half* __restrict__ wt,
    const float* __restrict__ bias, const float* __restrict__ attn_w,
    const int* __restrict__ dst, __half* __restrict__ zh,
    float* __restrict__ sv, float* __restrict__ tv, int* __restrict__ cursor)
{
    __shared__ _Float16 hA[16][136];
    __shared__ _Float16 wB[128][136];
    __shared__ float spart[4][16], tpart[4][16];

    const int tid = threadIdx.x;
    const int node0 = blockIdx.x << 4;

    // stage W^T fp16 into LDS: 128 rows x 128 halves = 2048 uint4,
    // 16 uint4 per row (uint4 = 8 halves).  [r = i>>4, seg = i&15]
    {
        const uint4* w4 = (const uint4*)wt;
        for (int i = tid; i < 2048; i += 256) {
            int r = i >> 4, seg = i & 15;
            *(uint4*)&wB[r][seg << 3] = w4[i];
        }
    }
    // stage h tile as fp16 (512 float4; 32 float4 per row)
    {
        const float4* h4 = (const float4*)(h + (size_t)node0 * 128);
        for (int i = tid; i < 512; i += 256) {
            int r = i >> 5, c4 = i & 31;
            float4 v = h4[i];
            union { __half2 h2[2]; uint2 u; } pk;
            pk.h2[0] = __floats2half2_rn(v.x, v.y);
            pk.h2[1] = __floats2half2_rn(v.z, v.w);
            *(uint2*)&hA[r][c4 << 2] = pk.u;
        }
    }
    __syncthreads();

    const int lane = tid & 63;
    const int wv = tid >> 6;          // wave 0..3
    const int l16 = lane & 15;
    const int oct = lane >> 4;
    const int n0 = wv << 5;           // this wave's 32-col strip

    floatx4 acc0 = {0.f, 0.f, 0.f, 0.f};
    floatx4 acc1 = {0.f, 0.f, 0.f, 0.f};
    #pragma unroll
    for (int kk = 0; kk < 4; ++kk) {
        const int k0 = kk << 5;
        half8 a  = *(const half8*)&hA[l16][k0 + (oct << 3)];
        half8 b0 = *(const half8*)&wB[n0 + l16][k0 + (oct << 3)];
        half8 b1 = *(const half8*)&wB[n0 + 16 + l16][k0 + (oct << 3)];
        acc0 = __builtin_amdgcn_mfma_f32_16x16x32_f16(a, b0, acc0, 0, 0, 0);
        acc1 = __builtin_amdgcn_mfma_f32_16x16x32_f16(a, b1, acc1, 0, 0, 0);
    }

    const float bv0 = bias[n0 + l16],         bv1 = bias[n0 + 16 + l16];
    const float ws0 = attn_w[n0 + l16],       ws1 = attn_w[n0 + 16 + l16];
    const float wd0 = attn_w[128 + n0 + l16], wd1 = attn_w[128 + n0 + 16 + l16];

    float s_acc[4], t_acc[4];
    #pragma unroll
    for (int r = 0; r < 4; ++r) {
        float z0 = clampinf(acc0[r] + bv0);
        float z1 = clampinf(acc1[r] + bv1);
        const int row = (oct << 2) + r;
        zh[(size_t)(node0 + row) * 128 + n0 + l16]      = __float2half(z0);
        zh[(size_t)(node0 + row) * 128 + n0 + 16 + l16] = __float2half(z1);
        s_acc[r] = z0 * ws0 + z1 * ws1;
        t_acc[r] = z0 * wd0 + z1 * wd1;
    }
    // reduce over the 16 cols (l16) inside each oct group
    #pragma unroll
    for (int r = 0; r < 4; ++r) {
        #pragma unroll
        for (int o = 1; o < 16; o <<= 1) {
            s_acc[r] += __shfl_xor(s_acc[r], o);
            t_acc[r] += __shfl_xor(t_acc[r], o);
        }
    }
    if (l16 == 0) {
        #pragma unroll
        for (int r = 0; r < 4; ++r) {
            spart[wv][(oct << 2) + r] = s_acc[r];
            tpart[wv][(oct << 2) + r] = t_acc[r];
        }
    }
    __syncthreads();
    if (tid < 16) {
        sv[node0 + tid] = spart[0][tid] + spart[1][tid] + spart[2][tid] + spart[3][tid];
        tv[node0 + tid] = tpart[0][tid] + tpart[1][tid] + tpart[2][tid] + tpart[3][tid];
    }

    // fused histogram: exactly one edge per thread (3125*256 == 800000)
    atomicAdd(&cursor[dst[blockIdx.x * 256 + tid]], 1);
}

// ---------------------------------------------------------------------------
// hierarchical scan: per-block sums -> root scan -> block-local scan
// ---------------------------------------------------------------------------
__global__ __launch_bounds__(256) void k_scan_bsum(const int* __restrict__ cursor,
                                                   int* __restrict__ bsum)
{
    __shared__ int s[256];
    const int t = threadIdx.x;
    const int idx = blockIdx.x * 256 + t;
    s[t] = (idx < N_NODES) ? cursor[idx] : 0;
    __syncthreads();
    for (int off = 128; off; off >>= 1) {
        if (t < off) s[t] += s[t + off];
        __syncthreads();
    }
    if (t == 0) bsum[blockIdx.x] = s[0];
}

__global__ __launch_bounds__(256) void k_scan_root(const int* __restrict__ bsum,
                                                   int* __restrict__ broot,
                                                   int* __restrict__ colptr)
{
    __shared__ int s[256];
    const int t = threadIdx.x;
    int v = (t < NBLK_SCAN) ? bsum[t] : 0;
    s[t] = v;
    __syncthreads();
    for (int off = 1; off < 256; off <<= 1) {
        int u = (t >= off) ? s[t - off] : 0;
        __syncthreads();
        s[t] += u;
        __syncthreads();
    }
    if (t < NBLK_SCAN) broot[t] = s[t] - v;      // exclusive
    if (t == 255) colptr[N_NODES] = s[255];
}

__global__ __launch_bounds__(256) void k_scan_final(const int* __restrict__ cursor_in,
                                                    const int* __restrict__ broot,
                                                    int* __restrict__ colptr,
                                                    int* __restrict__ cursor_out)
{
    __shared__ int s[256];
    const int t = threadIdx.x;
    const int idx = blockIdx.x * 256 + t;
    int v = (idx < N_NODES) ? cursor_in[idx] : 0;
    s[t] = v;
    __syncthreads();
    for (int off = 1; off < 256; off <<= 1) {
        int u = (t >= off) ? s[t - off] : 0;
        __syncthreads();
        s[t] += u;
        __syncthreads();
    }
    if (idx < N_NODES) {
        int pos = broot[blockIdx.x] + s[t] - v;
        colptr[idx] = pos;
        cursor_out[idx] = pos;
    }
}

// ---------------------------------------------------------------------------
// scatter edges into CSR order as ONE 16B record {src, sigma, e, pad}
// ---------------------------------------------------------------------------
__global__ void k_scatter(const int* __restrict__ src, const int* __restrict__ dst,
                          const float* __restrict__ sigma,
                          const float* __restrict__ sv, const float* __restrict__ tv,
                          const float* __restrict__ attn_b,
                          int* __restrict__ cursor, float4* __restrict__ recs)
{
    int e = blockIdx.x * 256 + threadIdx.x;
    if (e < N_EDGES) {
        int s = src[e];
        int d = dst[e];
        float a = sv[s] + tv[d] + attn_b[0];
        a = clampinf(a);
        float ev = a > 0.f ? a : 0.01f * a;      // leaky relu
        int pos = atomicAdd(&cursor[d], 1);
        float4 rec;
        rec.x = __int_as_float(s);
        rec.y = sigma[e];
        rec.z = ev;
        rec.w = 0.f;
        recs[pos] = rec;
    }
}

// ---------------------------------------------------------------------------
// K6: per-node softmax + weighted aggregate. One 64-lane wave per node.
// All __shfl executed wave-uniformly (ds_bpermute from inactive lanes is UB).
// ---------------------------------------------------------------------------
__global__ __launch_bounds__(256) void k_agg(
    const int* __restrict__ colptr, const float4* __restrict__ recs,
    const __half* __restrict__ zh, float* __restrict__ out)
{
    const int lane = threadIdx.x & 63;
    const int node = blockIdx.x * 4 + (threadIdx.x >> 6);
    if (node >= N_NODES) return;
    const int base = colptr[node];
    const int deg = colptr[node + 1] - base;

    const int grp = lane >> 4;   // 0..3: which edge of the 4 in flight
    const int l16 = lane & 15;   // feature octet within the row
    float acc[8] = {0.f, 0.f, 0.f, 0.f, 0.f, 0.f, 0.f, 0.f};

    if (deg > 0) {
        if (deg <= 64) {
            // ---- fast path: everything in registers ----
            int sidx = 0; float sig = 0.f, e = -INFINITY;
            if (lane < deg) {
                float4 r = recs[base + lane];
                sidx = __float_as_int(r.x); sig = r.y; e = r.z;
            }
            float m = e;
            for (int o = 32; o; o >>= 1) m = fmaxf(m, __shfl_xor(m, o));
            float p = (lane < deg) ? __expf(e - m) : 0.f;
            float dn = p, bs = sig;
            for (int o = 32; o; o >>= 1) {
                dn += __shfl_xor(dn, o);
                bs += __shfl_xor(bs, o);
            }
            const float coef = p * sig * (1.0f / dn) / (bs + 1e-6f);
            for (int c = 0; c < deg; c += 4) {
                const int j = c + grp;                 // j <= 63 always
                const int js = (j < deg) ? j : 0;      // clamp source index
                float cf = __shfl(coef, js);           // uniform: all lanes
                int sj = __shfl(sidx, js);
                if (j < deg) {
                    uint4 raw = *(const uint4*)(zh + ((size_t)sj << 7) + (l16 << 3));
                    const __half2* hp = (const __half2*)&raw;
                    #pragma unroll
                    for (int k = 0; k < 4; ++k) {
                        float2 f = __half22float2(hp[k]);
                        acc[2*k]   = fmaf(cf, f.x, acc[2*k]);
                        acc[2*k+1] = fmaf(cf, f.y, acc[2*k+1]);
                    }
                }
            }
        } else {
            // ---- generic path (deg > 64, rare) ----
            float m = -INFINITY;
            for (int i = lane; i < deg; i += 64) m = fmaxf(m, recs[base + i].z);
            for (int o = 32; o; o >>= 1) m = fmaxf(m, __shfl_xor(m, o));
            float dn = 0.f, bs = 0.f;
            for (int i = lane; i < deg; i += 64) {
                float4 r = recs[base + i];
                dn += __expf(r.z - m); bs += r.y;
            }
            for (int o = 32; o; o >>= 1) {
                dn += __shfl_xor(dn, o);
                bs += __shfl_xor(bs, o);
            }
            const float scale = (1.0f / dn) / (bs + 1e-6f);
            for (int c = 0; c < deg; c += 64) {
                int i = c + lane;
                int sidx = 0; float coef = 0.f;
                if (i < deg) {
                    float4 r = recs[base + i];
                    sidx = __float_as_int(r.x);
                    coef = __expf(r.z - m) * r.y * scale;
                }
                const int cnt = min(64, deg - c);
                for (int j = 0; j < cnt; j += 4) {
                    const int jj = j + grp;            // jj <= 63 always
                    const int js = (jj < cnt) ? jj : 0;
                    float cf = __shfl(coef, js);       // uniform: all lanes
                    int sj = __shfl(sidx, js);
                    if (jj < cnt) {
                        uint4 raw = *(const uint4*)(zh + ((size_t)sj << 7) + (l16 << 3));
                        const __half2* hp = (const __half2*)&raw;
                        #pragma unroll
                        for (int k = 0; k < 4; ++k) {
                            float2 f = __half22float2(hp[k]);
                            acc[2*k]   = fmaf(cf, f.x, acc[2*k]);
                            acc[2*k+1] = fmaf(cf, f.y, acc[2*k+1]);
                        }
                    }
                }
            }
        }
    }
    // combine the 4 groups: feature 8*l16+k lives in lanes {l16, l16+16, l16+32, l16+48}
    #pragma unroll
    for (int k = 0; k < 8; ++k) {
        acc[k] += __shfl_xor(acc[k], 16);
        acc[k] += __shfl_xor(acc[k], 32);
    }
    if (grp == 0) {
        float4 o0, o1;
        o0.x = clampinf(acc[0]); o0.y = clampinf(acc[1]);
        o0.z = clampinf(acc[2]); o0.w = clampinf(acc[3]);
        o1.x = clampinf(acc[4]); o1.y = clampinf(acc[5]);
        o1.z = clampinf(acc[6]); o1.w = clampinf(acc[7]);
        float4* op = (float4*)(out + (size_t)node * 128 + (l16 << 3));
        op[0] = o0; op[1] = o1;
    }
}

// ---------------------------------------------------------------------------
// BatchNorm: per-feature sum / sumsq partials + atomics, then fused apply+ELU
// ---------------------------------------------------------------------------
__global__ __launch_bounds__(256) void k_bnstats(const float* __restrict__ hnew,
                                                 float* __restrict__ sums)
{
    const int f = threadIdx.x & 127;
    const int half_ = threadIdx.x >> 7;
    float s = 0.f, q = 0.f;
    for (int node = blockIdx.x * 2 + half_; node < N_NODES; node += gridDim.x * 2) {
        float v = hnew[(size_t)node * 128 + f];
        s += v;
        q += v * v;
    }
    __shared__ float ls[256], lq[256];
    ls[threadIdx.x] = s; lq[threadIdx.x] = q;
    __syncthreads();
    if (half_ == 0) {
        s += ls[threadIdx.x + 128];
        q += lq[threadIdx.x + 128];
        atomicAdd(&sums[f], s);
        atomicAdd(&sums[128 + f], q);
    }
}

__global__ __launch_bounds__(256) void k_bnapply(float* __restrict__ io,
                                                 const float* __restrict__ sums,
                                                 const float* __restrict__ gamma,
                                                 const float* __restrict__ beta)
{
    const size_t idx = (size_t)blockIdx.x * 256 + threadIdx.x;
    const int f = (int)(idx & 127);
    const float invn = 1.0f / (float)N_NODES;
    float mu = sums[f] * invn;
    float var = fmaxf(sums[128 + f] * invn - mu * mu, 0.f);
    float rs = rsqrtf(var + 1e-5f);
    float x = io[idx];
    float y = (x - mu) * rs * gamma[f] + beta[f];
    io[idx] = y > 0.f ? y : expm1f(y);
}

// ---------------------------------------------------------------------------
extern "C" void kernel_launch(void* const* d_in, const int* in_sizes, int n_in,
                              void* d_out, int out_size, void* d_ws, size_t ws_size,
                              hipStream_t stream)
{
    const float* h      = (const float*)d_in[0];
    const int*   src    = (const int*)  d_in[1];
    const int*   dst    = (const int*)  d_in[2];
    const float* sigma  = (const float*)d_in[3];
    const float* fc_w   = (const float*)d_in[4];
    const float* fc_b   = (const float*)d_in[5];
    const float* attn_w = (const float*)d_in[6];
    const float* attn_b = (const float*)d_in[7];
    const float* gamma  = (const float*)d_in[8];
    const float* beta   = (const float*)d_in[9];
    float* out = (float*)d_out;

    // workspace layout (~27 MB)
    float4* recs   = (float4*)d_ws;                         // 800000 x 16B
    __half* zh     = (__half*)(recs + N_EDGES);             // 50000*128 fp16
    float*  sv     = (float*)(zh + (size_t)N_NODES * 128);  // 50000
    float*  tv     = sv + N_NODES;                          // 50000
    float*  bns    = tv + N_NODES;                          // 256
    int*    colptr = (int*)(bns + 256);                     // 50001 (pad 50004)
    int*    cursor = colptr + 50004;                        // 50000
    int*    bsum   = cursor + N_NODES;                      // 196 (pad 256)
    int*    broot  = bsum + 256;                            // 196 (pad 256)
    __half* wt     = (__half*)(broot + 256);                // 128*128 fp16 (W^T)

    hipMemsetAsync(cursor, 0, N_NODES * sizeof(int), stream);
    hipMemsetAsync(bns, 0, 256 * sizeof(float), stream);

    k_wcast     <<<64, 256, 0, stream>>>(fc_w, wt);
    k_gemm      <<<N_NODES / 16, 256, 0, stream>>>(h, wt, fc_b, attn_w, dst,
                                                   zh, sv, tv, cursor);
    k_scan_bsum <<<NBLK_SCAN, 256, 0, stream>>>(cursor, bsum);
    k_scan_root <<<1, 256, 0, stream>>>(bsum, broot, colptr);
    k_scan_final<<<NBLK_SCAN, 256, 0, stream>>>(cursor, broot, colptr, cursor);
    k_scatter   <<<N_EDGES / 256, 256, 0, stream>>>(src, dst, sigma, sv, tv, attn_b,
                                                    cursor, recs);
    k_agg       <<<N_NODES / 4, 256, 0, stream>>>(colptr, recs, zh, out);
    k_bnstats   <<<256, 256, 0, stream>>>(out, bns);
    k_bnapply   <<<(N_NODES * 128) / 256, 256, 0, stream>>>(out, bns, gamma, beta);
}